// Round 1
// baseline (289.290 us; speedup 1.0000x reference)
//
#include <hip/hip_runtime.h>
#include <stdint.h>
#include <stddef.h>

typedef __attribute__((ext_vector_type(8))) short short8;
typedef __attribute__((ext_vector_type(4))) float f32x4;

#define MFMA16(a, b, c) __builtin_amdgcn_mfma_f32_16x16x32_bf16((a), (b), (c), 0, 0, 0)

__device__ __forceinline__ unsigned short f2bf(float f) {
  unsigned int u = __builtin_bit_cast(unsigned int, f);
  u += 0x7fffu + ((u >> 16) & 1u);
  return (unsigned short)(u >> 16);
}

__device__ __forceinline__ short8 mk8(const unsigned short* p) {
  return *(const short8*)p;
}

// swizzled offset into a [rows][40]-half LDS tile holding 32 data cols:
// 16B slot index (c>>3) XOR'd with (row>>3)&3 -> 2-way conflicts only (free).
__device__ __forceinline__ int swz40(int row, int c) {
  return row * 40 + ((((c >> 3) ^ (row >> 3)) & 3) << 3) + (c & 7);
}

// ---------------- kernel 0: cast weights to bf16 ----------------
__global__ __launch_bounds__(256) void k_prep(const float* __restrict__ wq,
                                              const float* __restrict__ wo,
                                              unsigned short* __restrict__ wq_bf,
                                              unsigned short* __restrict__ wo_bf) {
  int i = blockIdx.x * 256 + threadIdx.x;
  if (i < 98304) wq_bf[i] = f2bf(wq[i]);
  if (i < 32768) wo_bf[i] = f2bf(wo[i]);
}

// ---------------- kernel 1: per-pixel rsqrt(mean(x^2)+eps) ----------------
__global__ __launch_bounds__(256) void k_rms(const float* __restrict__ x,
                                             float* __restrict__ rbuf) {
  __shared__ float part[4][64];
  int bid = blockIdx.x;            // 256 blocks: b = bid>>6, 64 pixels each
  int b = bid >> 6;
  int p0 = (bid & 63) * 64;
  int t = threadIdx.x;
  int pl = t & 63;
  int cp = t >> 6;                 // 4 c-partitions of 64 channels
  const float* xb = x + (size_t)b * 256 * 4096 + p0 + pl;
  float s = 0.f;
  for (int c = cp * 64; c < cp * 64 + 64; ++c) {
    float v = xb[(size_t)c * 4096];
    s += v * v;
  }
  part[cp][pl] = s;
  __syncthreads();
  if (t < 64) {
    float tot = part[0][t] + part[1][t] + part[2][t] + part[3][t];
    rbuf[b * 4096 + p0 + t] = rsqrtf(tot * (1.0f / 256.0f) + 1e-12f);
  }
}

// ---------------- kernel 2: fused RMSNorm + QKV GEMM ----------------
// qkv[b][o][p] = sum_c W[o][c] * (x[b][c][p]*r[b][p]*g[c]),  o in [0,384)
// block: 64 o x 128 p, 4 waves (16 o-rows each), K=256 in chunks of 32.
__global__ __launch_bounds__(256) void k_qkv(const float* __restrict__ x,
                                             const float* __restrict__ g,
                                             const unsigned short* __restrict__ wq_bf,
                                             const float* __restrict__ rbuf,
                                             unsigned short* __restrict__ qkvb) {
  int bid = blockIdx.x;            // 768 = 4b * 6ot * 32pt
  int b = bid / 192;
  int rem = bid % 192;
  int ot = rem / 32;
  int pt = rem % 32;
  int o0 = ot * 64, p0 = pt * 128;

  __shared__ unsigned short xnT[128 * 40];   // [p][c-chunk], swizzled

  int t = threadIdx.x;
  int lane = t & 63, w = t >> 6;
  int lr = lane & 15, lg = lane >> 4;
  int pl = t & 127, ch = t >> 7;             // staging: 2 groups x 16 channels

  float rr = rbuf[b * 4096 + p0 + pl];
  const float* xb = x + (size_t)b * 256 * 4096;
  const unsigned short* wqrow = wq_bf + (size_t)(o0 + w * 16 + lr) * 256;

  f32x4 acc[8];
  f32x4 z = {0.f, 0.f, 0.f, 0.f};
#pragma unroll
  for (int i = 0; i < 8; ++i) acc[i] = z;

  for (int c0 = 0; c0 < 256; c0 += 32) {
    __syncthreads();
    // stage 32 c x 128 p normalized bf16, transposed into LDS
#pragma unroll
    for (int i = 0; i < 8; ++i) {
      int c = ch * 16 + i * 2;
      float v0 = xb[(size_t)(c0 + c) * 4096 + p0 + pl];
      float v1 = xb[(size_t)(c0 + c + 1) * 4096 + p0 + pl];
      v0 = v0 * rr * g[c0 + c];
      v1 = v1 * rr * g[c0 + c + 1];
      unsigned int u = (unsigned int)f2bf(v0) | ((unsigned int)f2bf(v1) << 16);
      *(unsigned int*)&xnT[swz40(pl, c)] = u;
    }
    __syncthreads();
    short8 af = mk8(wqrow + c0 + lg * 8);
#pragma unroll
    for (int pt16 = 0; pt16 < 8; ++pt16) {
      short8 bf = mk8(&xnT[swz40(pt16 * 16 + lr, lg * 8)]);
      acc[pt16] = MFMA16(af, bf, acc[pt16]);
    }
  }

  unsigned short* qb = qkvb + (size_t)b * 384 * 4096;
#pragma unroll
  for (int pt16 = 0; pt16 < 8; ++pt16) {
#pragma unroll
    for (int r = 0; r < 4; ++r) {
      int o = o0 + w * 16 + lg * 4 + r;      // D row = (lane>>4)*4+reg
      int p = p0 + pt16 * 16 + lr;           // D col = lane&15
      qb[(size_t)o * 4096 + p] = f2bf(acc[pt16][r]);
    }
  }
}

// ---------------- kernel 3: flash attention ----------------
// grid 1024 = 16 (b,h) x 64 q-tiles of 64 rows; 4 waves x 16 q-rows.
__global__ __launch_bounds__(256) void k_attn(const unsigned short* __restrict__ qkvb,
                                              unsigned short* __restrict__ attno) {
  int bid = blockIdx.x;
  int qt = bid & 63, bh = bid >> 6;
  int b = bh >> 2, h = bh & 3;
  int t = threadIdx.x, lane = t & 63, w = t >> 6;
  int lr = lane & 15, lg = lane >> 4;

  __shared__ unsigned short Kt[64 * 40];     // K^T tile [j][d], swizzled
  __shared__ unsigned short Vt[32 * 72];     // V tile [d][j], padded
  __shared__ unsigned short Pl[4][16 * 72];  // per-wave P [q][j], padded

  const unsigned short* qg = qkvb + ((size_t)b * 384 + h * 32) * 4096;
  const unsigned short* kgp = qkvb + ((size_t)b * 384 + 128 + h * 32) * 4096;
  const unsigned short* vgp = qkvb + ((size_t)b * 384 + 256 + h * 32) * 4096;

  // Q fragment (A layout): lane holds Q[p=lr][d=lg*8+i]
  int qrow = qt * 64 + w * 16 + lr;
  short8 qf;
#pragma unroll
  for (int i = 0; i < 8; ++i) qf[i] = (short)qg[(size_t)(lg * 8 + i) * 4096 + qrow];

  f32x4 z = {0.f, 0.f, 0.f, 0.f};
  f32x4 oacc[2] = {z, z};
  float m[4], lsum[4];
#pragma unroll
  for (int r = 0; r < 4; ++r) { m[r] = -1e30f; lsum[r] = 0.f; }
  const float cexp = 0.17677669529663687f * 1.4426950408889634f; // scale*log2(e)

  int jj = t & 63, dgrp = t >> 6;
  const unsigned short* krow0 = kgp + (size_t)(dgrp * 8) * 4096;
  const unsigned short* vrow0 = vgp + (size_t)(dgrp * 8) * 4096;

  for (int k0 = 0; k0 < 4096; k0 += 64) {
    __syncthreads();
    // stage K tile transposed (row jj, 8 d-values -> one b128 write)
    short8 kpack;
#pragma unroll
    for (int i = 0; i < 8; ++i)
      kpack[i] = (short)krow0[(size_t)i * 4096 + k0 + jj];
    *(short8*)&Kt[swz40(jj, dgrp * 8)] = kpack;
    // stage V tile straight [d][j]
#pragma unroll
    for (int i = 0; i < 8; ++i)
      Vt[(dgrp * 8 + i) * 72 + jj] = vrow0[(size_t)i * 4096 + k0 + jj];
    __syncthreads();

    // S = Q K^T : 4 tiles of 16q x 16j
    f32x4 s[4];
#pragma unroll
    for (int tt = 0; tt < 4; ++tt) {
      short8 kf = mk8(&Kt[swz40(tt * 16 + lr, lg * 8)]);
      s[tt] = MFMA16(qf, kf, z);
    }

    // online softmax (rows = lg*4+r, cols across 16-lane group)
    float fac[4];
#pragma unroll
    for (int r = 0; r < 4; ++r) {
      float mx = fmaxf(fmaxf(s[0][r], s[1][r]), fmaxf(s[2][r], s[3][r]));
      mx = fmaxf(mx, __shfl_xor(mx, 1, 16));
      mx = fmaxf(mx, __shfl_xor(mx, 2, 16));
      mx = fmaxf(mx, __shfl_xor(mx, 4, 16));
      mx = fmaxf(mx, __shfl_xor(mx, 8, 16));
      float mn = fmaxf(m[r], mx);
      fac[r] = exp2f((m[r] - mn) * cexp);
      m[r] = mn;
    }
#pragma unroll
    for (int tt = 0; tt < 4; ++tt)
#pragma unroll
      for (int r = 0; r < 4; ++r)
        s[tt][r] = exp2f((s[tt][r] - m[r]) * cexp);
#pragma unroll
    for (int r = 0; r < 4; ++r) {
      float rs = s[0][r] + s[1][r] + s[2][r] + s[3][r];
      rs += __shfl_xor(rs, 1, 16);
      rs += __shfl_xor(rs, 2, 16);
      rs += __shfl_xor(rs, 4, 16);
      rs += __shfl_xor(rs, 8, 16);
      lsum[r] = lsum[r] * fac[r] + rs;
    }
#pragma unroll
    for (int dt = 0; dt < 2; ++dt)
#pragma unroll
      for (int r = 0; r < 4; ++r) oacc[dt][r] *= fac[r];

    // P -> LDS (D layout in, A layout out)
#pragma unroll
    for (int tt = 0; tt < 4; ++tt)
#pragma unroll
      for (int r = 0; r < 4; ++r)
        Pl[w][(lg * 4 + r) * 72 + tt * 16 + lr] = f2bf(s[tt][r]);

    // O += P V
#pragma unroll
    for (int kc = 0; kc < 2; ++kc) {
      short8 pf = mk8(&Pl[w][lr * 72 + kc * 32 + lg * 8]);
#pragma unroll
      for (int dt = 0; dt < 2; ++dt) {
        short8 vf = mk8(&Vt[(dt * 16 + lr) * 72 + kc * 32 + lg * 8]);
        oacc[dt] = MFMA16(pf, vf, oacc[dt]);
      }
    }
  }

  // epilogue: divide by row-sum, store [b][p][h*32+dd]
  unsigned short* ob = attno + (size_t)b * 4096 * 128 + h * 32;
#pragma unroll
  for (int dt = 0; dt < 2; ++dt) {
#pragma unroll
    for (int r = 0; r < 4; ++r) {
      int p = qt * 64 + w * 16 + lg * 4 + r;
      float val = oacc[dt][r] / lsum[r];
      ob[(size_t)p * 128 + dt * 16 + lr] = f2bf(val);
    }
  }
}

// ---------------- kernel 4: output projection + bias ----------------
// out[b][co][p] = sum_ci attno[b][p][ci] * wo[co][ci] + bo[co]
__global__ __launch_bounds__(256) void k_out(const unsigned short* __restrict__ attno,
                                             const unsigned short* __restrict__ wo_bf,
                                             const float* __restrict__ bo,
                                             float* __restrict__ out) {
  int bid = blockIdx.x;            // 256 = 4b * 64 p-tiles of 64
  int b = bid >> 6;
  int p0 = (bid & 63) * 64;
  int t = threadIdx.x, lane = t & 63, w = t >> 6;
  int lr = lane & 15, lg = lane >> 4;

  f32x4 z = {0.f, 0.f, 0.f, 0.f};
  f32x4 acc[4][4];
#pragma unroll
  for (int i = 0; i < 4; ++i)
#pragma unroll
    for (int j = 0; j < 4; ++j) acc[i][j] = z;

  for (int c0 = 0; c0 < 128; c0 += 32) {
    short8 bfr[4];
#pragma unroll
    for (int pt16 = 0; pt16 < 4; ++pt16)
      bfr[pt16] = mk8(attno + (size_t)(b * 4096 + p0 + pt16 * 16 + lr) * 128 + c0 + lg * 8);
#pragma unroll
    for (int ct = 0; ct < 4; ++ct) {
      short8 afr = mk8(wo_bf + (size_t)(w * 64 + ct * 16 + lr) * 128 + c0 + lg * 8);
#pragma unroll
      for (int pt16 = 0; pt16 < 4; ++pt16)
        acc[ct][pt16] = MFMA16(afr, bfr[pt16], acc[ct][pt16]);
    }
  }

#pragma unroll
  for (int ct = 0; ct < 4; ++ct) {
#pragma unroll
    for (int pt16 = 0; pt16 < 4; ++pt16) {
#pragma unroll
      for (int r = 0; r < 4; ++r) {
        int co = w * 64 + ct * 16 + lg * 4 + r;
        int p = p0 + pt16 * 16 + lr;
        out[((size_t)b * 256 + co) * 4096 + p] = acc[ct][pt16][r] + bo[co];
      }
    }
  }
}

extern "C" void kernel_launch(void* const* d_in, const int* in_sizes, int n_in,
                              void* d_out, int out_size, void* d_ws, size_t ws_size,
                              hipStream_t stream) {
  const float* x = (const float*)d_in[0];
  const float* g = (const float*)d_in[1];
  const float* wq = (const float*)d_in[2];
  const float* wo = (const float*)d_in[3];
  const float* bo = (const float*)d_in[4];
  float* out = (float*)d_out;

  char* ws = (char*)d_ws;
  float* rbuf = (float*)ws;                                  // 65536 B
  unsigned short* wq_bf = (unsigned short*)(ws + 65536);     // 196608 B
  unsigned short* wo_bf = (unsigned short*)(ws + 262144);    // 65536 B
  unsigned short* qkvb = (unsigned short*)(ws + 327680);     // 12582912 B
  unsigned short* attno = (unsigned short*)(ws + 12910592);  // 4194304 B

  k_prep<<<dim3(384), dim3(256), 0, stream>>>(wq, wo, wq_bf, wo_bf);
  k_rms<<<dim3(256), dim3(256), 0, stream>>>(x, rbuf);
  k_qkv<<<dim3(768), dim3(256), 0, stream>>>(x, g, wq_bf, rbuf, qkvb);
  k_attn<<<dim3(1024), dim3(256), 0, stream>>>(qkvb, attno);
  k_out<<<dim3(256), dim3(256), 0, stream>>>(attno, wo_bf, bo, out);
}

// Round 2
// 266.437 us; speedup vs baseline: 1.0858x; 1.0858x over previous
//
#include <hip/hip_runtime.h>
#include <stdint.h>
#include <stddef.h>

typedef __attribute__((ext_vector_type(8))) short short8;
typedef __attribute__((ext_vector_type(4))) float f32x4;

#define MFMA16(a, b, c) __builtin_amdgcn_mfma_f32_16x16x32_bf16((a), (b), (c), 0, 0, 0)

__device__ __forceinline__ unsigned short f2bf(float f) {
  unsigned int u = __builtin_bit_cast(unsigned int, f);
  u += 0x7fffu + ((u >> 16) & 1u);
  return (unsigned short)(u >> 16);
}

__device__ __forceinline__ short8 mk8(const unsigned short* p) {
  return *(const short8*)p;
}

// swizzled offset into a [rows][40]-half LDS tile holding 32 data cols.
__device__ __forceinline__ int swz40(int row, int c) {
  return row * 40 + ((((c >> 3) ^ (row >> 3)) & 3) << 3) + (c & 7);
}

// ---------------- kernel 0: cast weights to bf16 ----------------
__global__ __launch_bounds__(256) void k_prep(const float* __restrict__ wq,
                                              const float* __restrict__ wo,
                                              unsigned short* __restrict__ wq_bf,
                                              unsigned short* __restrict__ wo_bf) {
  int i = blockIdx.x * 256 + threadIdx.x;
  if (i < 98304) wq_bf[i] = f2bf(wq[i]);
  if (i < 32768) wo_bf[i] = f2bf(wo[i]);
}

// ---------------- kernel 1: per-pixel rsqrt(mean(x^2)+eps) ----------------
__global__ __launch_bounds__(256) void k_rms(const float* __restrict__ x,
                                             float* __restrict__ rbuf) {
  __shared__ float part[4][64];
  int bid = blockIdx.x;
  int b = bid >> 6;
  int p0 = (bid & 63) * 64;
  int t = threadIdx.x;
  int pl = t & 63;
  int cp = t >> 6;
  const float* xb = x + (size_t)b * 256 * 4096 + p0 + pl;
  float s = 0.f;
  for (int c = cp * 64; c < cp * 64 + 64; ++c) {
    float v = xb[(size_t)c * 4096];
    s += v * v;
  }
  part[cp][pl] = s;
  __syncthreads();
  if (t < 64) {
    float tot = part[0][t] + part[1][t] + part[2][t] + part[3][t];
    rbuf[b * 4096 + p0 + t] = rsqrtf(tot * (1.0f / 256.0f) + 1e-12f);
  }
}

// ---------------- kernel 2: fused RMSNorm + QKV GEMM ----------------
// Output layouts:
//   Q: [bh][p][d]  (d contiguous)   qbuf + (bh*4096 + p)*32 + d
//   K: [bh][p][d]                   kbuf + (bh*4096 + p)*32 + d
//   V: [bh][d][p]                   vbuf + (bh*32 + d)*4096 + p
__global__ __launch_bounds__(256) void k_qkv(const float* __restrict__ x,
                                             const float* __restrict__ g,
                                             const unsigned short* __restrict__ wq_bf,
                                             const float* __restrict__ rbuf,
                                             unsigned short* __restrict__ qbuf,
                                             unsigned short* __restrict__ kbuf,
                                             unsigned short* __restrict__ vbuf) {
  int bid = blockIdx.x;            // 768 = 4b * 6ot * 32pt
  int b = bid / 192;
  int rem = bid % 192;
  int ot = rem / 32;
  int pt = rem % 32;
  int o0 = ot * 64, p0 = pt * 128;

  __shared__ unsigned short xnT[128 * 40];

  int t = threadIdx.x;
  int lane = t & 63, w = t >> 6;
  int lr = lane & 15, lg = lane >> 4;
  int pl = t & 127, ch = t >> 7;

  float rr = rbuf[b * 4096 + p0 + pl];
  const float* xb = x + (size_t)b * 256 * 4096;
  const unsigned short* wqrow = wq_bf + (size_t)(o0 + w * 16 + lr) * 256;

  f32x4 acc[8];
  f32x4 z = {0.f, 0.f, 0.f, 0.f};
#pragma unroll
  for (int i = 0; i < 8; ++i) acc[i] = z;

  for (int c0 = 0; c0 < 256; c0 += 32) {
    __syncthreads();
#pragma unroll
    for (int i = 0; i < 8; ++i) {
      int c = ch * 16 + i * 2;
      float v0 = xb[(size_t)(c0 + c) * 4096 + p0 + pl];
      float v1 = xb[(size_t)(c0 + c + 1) * 4096 + p0 + pl];
      v0 = v0 * rr * g[c0 + c];
      v1 = v1 * rr * g[c0 + c + 1];
      unsigned int u = (unsigned int)f2bf(v0) | ((unsigned int)f2bf(v1) << 16);
      *(unsigned int*)&xnT[swz40(pl, c)] = u;
    }
    __syncthreads();
    short8 af = mk8(wqrow + c0 + lg * 8);
#pragma unroll
    for (int pt16 = 0; pt16 < 8; ++pt16) {
      short8 bf = mk8(&xnT[swz40(pt16 * 16 + lr, lg * 8)]);
      acc[pt16] = MFMA16(af, bf, acc[pt16]);
    }
  }

  // Epilogue: o row = o0 + w*16 + lg*4 + r, p col = p0 + pt16*16 + lr
  int obase = o0 + w * 16 + lg * 4;          // multiple of 4
  if (obase < 256) {
    // Q (o<128) or K: store [bh][p][d], 4 consecutive d -> one 8B store
    int isK = obase >= 128;
    int oh = obase - (isK ? 128 : 0);
    int h = oh >> 5, d0 = oh & 31;
    unsigned short* dst = (isK ? kbuf : qbuf) + ((size_t)(b * 4 + h) * 4096) * 32;
#pragma unroll
    for (int pt16 = 0; pt16 < 8; ++pt16) {
      int p = p0 + pt16 * 16 + lr;
      unsigned int u0 = (unsigned int)f2bf(acc[pt16][0]) | ((unsigned int)f2bf(acc[pt16][1]) << 16);
      unsigned int u1 = (unsigned int)f2bf(acc[pt16][2]) | ((unsigned int)f2bf(acc[pt16][3]) << 16);
      uint2 uu = {u0, u1};
      *(uint2*)(dst + (size_t)p * 32 + d0) = uu;
    }
  } else {
    // V: store [bh][d][p]
    int oh = obase - 256;
    int h = oh >> 5, d0 = oh & 31;
    unsigned short* dst = vbuf + ((size_t)(b * 4 + h) * 32) * 4096;
#pragma unroll
    for (int pt16 = 0; pt16 < 8; ++pt16) {
      int p = p0 + pt16 * 16 + lr;
#pragma unroll
      for (int r = 0; r < 4; ++r)
        dst[(size_t)(d0 + r) * 4096 + p] = f2bf(acc[pt16][r]);
    }
  }
}

// ---------------- kernel 3: flash attention (barrier-free) ----------------
// grid 1024 = 16 bh x 64 q-tiles of 64 rows; 4 waves x 16 q-rows.
// K/V fragments loaded directly from global (L1/L2-resident), no staging.
__global__ __launch_bounds__(256) void k_attn(const unsigned short* __restrict__ qbuf,
                                              const unsigned short* __restrict__ kbuf,
                                              const unsigned short* __restrict__ vbuf,
                                              unsigned short* __restrict__ attno) {
  int bid = blockIdx.x;
  int qt = bid & 63, bh = bid >> 6;
  int t = threadIdx.x, lane = t & 63, w = t >> 6;
  int lr = lane & 15, lg = lane >> 4;

  __shared__ unsigned short Pl[4][16 * 80];  // per-wave P [q][j], stride 80 (16B-aligned rows)

  const unsigned short* qg = qbuf + (size_t)bh * 4096 * 32;
  const unsigned short* kg = kbuf + (size_t)bh * 4096 * 32;
  const unsigned short* vg = vbuf + (size_t)bh * 32 * 4096;

  int qrow = qt * 64 + w * 16 + lr;
  short8 qf = mk8(qg + (size_t)qrow * 32 + lg * 8);

  f32x4 z = {0.f, 0.f, 0.f, 0.f};
  f32x4 oacc[2] = {z, z};
  float m[4], lsum[4];
#pragma unroll
  for (int r = 0; r < 4; ++r) { m[r] = -1e30f; lsum[r] = 0.f; }
  const float cexp = 0.17677669529663687f * 1.4426950408889634f; // scale*log2(e)

  unsigned short* plw = &Pl[w][0];

  // preload K fragments for tile 0
  short8 kf[4];
#pragma unroll
  for (int tt = 0; tt < 4; ++tt)
    kf[tt] = mk8(kg + (size_t)(tt * 16 + lr) * 32 + lg * 8);

  for (int k0 = 0; k0 < 4096; k0 += 64) {
    // V fragments for current tile (B-operand: lane holds V^T[d=lr'][j contiguous])
    short8 vf[4];
#pragma unroll
    for (int dt = 0; dt < 2; ++dt)
#pragma unroll
      for (int kc = 0; kc < 2; ++kc)
        vf[dt * 2 + kc] = mk8(vg + (size_t)(dt * 16 + lr) * 4096 + k0 + kc * 32 + lg * 8);

    // S = Q K^T
    f32x4 s[4];
#pragma unroll
    for (int tt = 0; tt < 4; ++tt) s[tt] = MFMA16(qf, kf[tt], z);

    // prefetch next K tile (wrap-indexed, branchless)
    int kn = (k0 + 64) & 4095;
#pragma unroll
    for (int tt = 0; tt < 4; ++tt)
      kf[tt] = mk8(kg + (size_t)(kn + tt * 16 + lr) * 32 + lg * 8);

    // online softmax (rows lg*4+r, cols across 16-lane group)
    float fac[4], mce[4];
#pragma unroll
    for (int r = 0; r < 4; ++r) {
      float mx = fmaxf(fmaxf(s[0][r], s[1][r]), fmaxf(s[2][r], s[3][r]));
      mx = fmaxf(mx, __shfl_xor(mx, 1, 16));
      mx = fmaxf(mx, __shfl_xor(mx, 2, 16));
      mx = fmaxf(mx, __shfl_xor(mx, 4, 16));
      mx = fmaxf(mx, __shfl_xor(mx, 8, 16));
      float mn = fmaxf(m[r], mx);
      fac[r] = __builtin_amdgcn_exp2f((m[r] - mn) * cexp);
      m[r] = mn;
      mce[r] = mn * cexp;
    }
#pragma unroll
    for (int tt = 0; tt < 4; ++tt)
#pragma unroll
      for (int r = 0; r < 4; ++r)
        s[tt][r] = __builtin_amdgcn_exp2f(fmaf(s[tt][r], cexp, -mce[r]));
#pragma unroll
    for (int r = 0; r < 4; ++r)
      lsum[r] = lsum[r] * fac[r] + ((s[0][r] + s[1][r]) + (s[2][r] + s[3][r]));
#pragma unroll
    for (int dt = 0; dt < 2; ++dt)
#pragma unroll
      for (int r = 0; r < 4; ++r) oacc[dt][r] *= fac[r];

    // P -> wave-private LDS (transpose D-layout -> A-layout)
    asm volatile("s_waitcnt lgkmcnt(0)" ::: "memory");  // WAR vs prev iter's reads
#pragma unroll
    for (int tt = 0; tt < 4; ++tt)
#pragma unroll
      for (int r = 0; r < 4; ++r)
        plw[(lg * 4 + r) * 80 + tt * 16 + lr] = f2bf(s[tt][r]);
    asm volatile("s_waitcnt lgkmcnt(0)" ::: "memory");
    __builtin_amdgcn_sched_barrier(0);

    // O += P V
#pragma unroll
    for (int kc = 0; kc < 2; ++kc) {
      short8 pf = mk8(plw + lr * 80 + kc * 32 + lg * 8);
#pragma unroll
      for (int dt = 0; dt < 2; ++dt)
        oacc[dt] = MFMA16(pf, vf[dt * 2 + kc], oacc[dt]);
    }
  }

  // reduce per-lane partial sums across the 16-lane group
#pragma unroll
  for (int r = 0; r < 4; ++r) {
    lsum[r] += __shfl_xor(lsum[r], 1, 16);
    lsum[r] += __shfl_xor(lsum[r], 2, 16);
    lsum[r] += __shfl_xor(lsum[r], 4, 16);
    lsum[r] += __shfl_xor(lsum[r], 8, 16);
  }
  float rinv[4];
#pragma unroll
  for (int r = 0; r < 4; ++r) rinv[r] = 1.0f / lsum[r];

  int b = bh >> 2, h = bh & 3;
  unsigned short* ob = attno + (size_t)b * 4096 * 128 + h * 32;
#pragma unroll
  for (int dt = 0; dt < 2; ++dt) {
#pragma unroll
    for (int r = 0; r < 4; ++r) {
      int p = qt * 64 + w * 16 + lg * 4 + r;
      ob[(size_t)p * 128 + dt * 16 + lr] = f2bf(oacc[dt][r] * rinv[r]);
    }
  }
}

// ---------------- kernel 4: output projection + bias ----------------
__global__ __launch_bounds__(256) void k_out(const unsigned short* __restrict__ attno,
                                             const unsigned short* __restrict__ wo_bf,
                                             const float* __restrict__ bo,
                                             float* __restrict__ out) {
  int bid = blockIdx.x;
  int b = bid >> 6;
  int p0 = (bid & 63) * 64;
  int t = threadIdx.x, lane = t & 63, w = t >> 6;
  int lr = lane & 15, lg = lane >> 4;

  f32x4 z = {0.f, 0.f, 0.f, 0.f};
  f32x4 acc[4][4];
#pragma unroll
  for (int i = 0; i < 4; ++i)
#pragma unroll
    for (int j = 0; j < 4; ++j) acc[i][j] = z;

  for (int c0 = 0; c0 < 128; c0 += 32) {
    short8 bfr[4];
#pragma unroll
    for (int pt16 = 0; pt16 < 4; ++pt16)
      bfr[pt16] = mk8(attno + (size_t)(b * 4096 + p0 + pt16 * 16 + lr) * 128 + c0 + lg * 8);
#pragma unroll
    for (int ct = 0; ct < 4; ++ct) {
      short8 afr = mk8(wo_bf + (size_t)(w * 64 + ct * 16 + lr) * 128 + c0 + lg * 8);
#pragma unroll
      for (int pt16 = 0; pt16 < 4; ++pt16)
        acc[ct][pt16] = MFMA16(afr, bfr[pt16], acc[ct][pt16]);
    }
  }

#pragma unroll
  for (int ct = 0; ct < 4; ++ct) {
#pragma unroll
    for (int pt16 = 0; pt16 < 4; ++pt16) {
#pragma unroll
      for (int r = 0; r < 4; ++r) {
        int co = w * 64 + ct * 16 + lg * 4 + r;
        int p = p0 + pt16 * 16 + lr;
        out[((size_t)b * 256 + co) * 4096 + p] = acc[ct][pt16][r] + bo[co];
      }
    }
  }
}

extern "C" void kernel_launch(void* const* d_in, const int* in_sizes, int n_in,
                              void* d_out, int out_size, void* d_ws, size_t ws_size,
                              hipStream_t stream) {
  const float* x = (const float*)d_in[0];
  const float* g = (const float*)d_in[1];
  const float* wq = (const float*)d_in[2];
  const float* wo = (const float*)d_in[3];
  const float* bo = (const float*)d_in[4];
  float* out = (float*)d_out;

  char* ws = (char*)d_ws;
  float* rbuf = (float*)ws;                                  // 65536 B
  unsigned short* wq_bf = (unsigned short*)(ws + 65536);     // 196608 B
  unsigned short* wo_bf = (unsigned short*)(ws + 262144);    // 65536 B
  unsigned short* qbuf = (unsigned short*)(ws + 327680);     // 4 MiB
  unsigned short* kbuf = (unsigned short*)(ws + 4521984);    // 4 MiB
  unsigned short* vbuf = (unsigned short*)(ws + 8716288);    // 4 MiB
  unsigned short* attno = (unsigned short*)(ws + 12910592);  // 4 MiB

  k_prep<<<dim3(384), dim3(256), 0, stream>>>(wq, wo, wq_bf, wo_bf);
  k_rms<<<dim3(256), dim3(256), 0, stream>>>(x, rbuf);
  k_qkv<<<dim3(768), dim3(256), 0, stream>>>(x, g, wq_bf, rbuf, qbuf, kbuf, vbuf);
  k_attn<<<dim3(1024), dim3(256), 0, stream>>>(qbuf, kbuf, vbuf, attno);
  k_out<<<dim3(256), dim3(256), 0, stream>>>(attno, wo_bf, bo, out);
}

// Round 5
// 145.849 us; speedup vs baseline: 1.9835x; 1.8268x over previous
//
#include <hip/hip_runtime.h>
#include <stdint.h>
#include <stddef.h>

typedef __attribute__((ext_vector_type(8))) short short8;
typedef __attribute__((ext_vector_type(4))) float f32x4;
typedef __attribute__((ext_vector_type(16))) float f32x16;
typedef __attribute__((ext_vector_type(4))) unsigned int uint4v;

#define MFMA16(a, b, c) __builtin_amdgcn_mfma_f32_16x16x32_bf16((a), (b), (c), 0, 0, 0)
#define MFMA32(a, b, c) __builtin_amdgcn_mfma_f32_32x32x16_bf16((a), (b), (c), 0, 0, 0)

__device__ __forceinline__ unsigned short f2bf(float f) {
  unsigned int u = __builtin_bit_cast(unsigned int, f);
  u += 0x7fffu + ((u >> 16) & 1u);
  return (unsigned short)(u >> 16);
}

__device__ __forceinline__ unsigned int pk2(float lo, float hi) {
  return (unsigned int)f2bf(lo) | ((unsigned int)f2bf(hi) << 16);
}

__device__ __forceinline__ short8 mk8(const unsigned short* p) {
  return *(const short8*)p;
}

// cross-half (lane^32) reductions via validated __shfl_xor primitive
__device__ __forceinline__ float redmax32(float v) {
  return fmaxf(v, __shfl_xor(v, 32));
}
__device__ __forceinline__ float redsum32(float v) {
  return v + __shfl_xor(v, 32);
}

__device__ __forceinline__ f32x16 zero16() {
  f32x16 v;
#pragma unroll
  for (int i = 0; i < 16; ++i) v[i] = 0.f;
  return v;
}

// swizzled offset into a [rows][40]-half LDS tile holding 32 data cols.
__device__ __forceinline__ int swz40(int row, int c) {
  return row * 40 + ((((c >> 3) ^ (row >> 3)) & 3) << 3) + (c & 7);
}

// ---------------- kernel 0: cast weights to bf16 ----------------
__global__ __launch_bounds__(256) void k_prep(const float* __restrict__ wq,
                                              const float* __restrict__ wo,
                                              unsigned short* __restrict__ wq_bf,
                                              unsigned short* __restrict__ wo_bf) {
  int i = blockIdx.x * 256 + threadIdx.x;
  if (i < 98304) wq_bf[i] = f2bf(wq[i]);
  if (i < 32768) wo_bf[i] = f2bf(wo[i]);
}

// ---------------- kernel 1: per-pixel rsqrt(mean(x^2)+eps) ----------------
__global__ __launch_bounds__(256) void k_rms(const float* __restrict__ x,
                                             float* __restrict__ rbuf) {
  __shared__ float part[4][64];
  int bid = blockIdx.x;
  int b = bid >> 6;
  int p0 = (bid & 63) * 64;
  int t = threadIdx.x;
  int pl = t & 63;
  int cp = t >> 6;
  const float* xb = x + (size_t)b * 256 * 4096 + p0 + pl;
  float s = 0.f;
  for (int c = cp * 64; c < cp * 64 + 64; ++c) {
    float v = xb[(size_t)c * 4096];
    s += v * v;
  }
  part[cp][pl] = s;
  __syncthreads();
  if (t < 64) {
    float tot = part[0][t] + part[1][t] + part[2][t] + part[3][t];
    rbuf[b * 4096 + p0 + t] = rsqrtf(tot * (1.0f / 256.0f) + 1e-12f);
  }
}

// ---------------- kernel 2: fused RMSNorm + QKV GEMM ----------------
// Output layouts:
//   Q, K: [bh][p][d]   buf + (bh*4096 + p)*32 + d
//   V:    [bh][d][p']  vbuf + (bh*32 + d)*4096 + p', where p' permutes the
//         low 4 bits of p by sigma (swap bit2<->bit3) to match the PV MFMA
//         k-slot ordering: slot k holds j = (k&3)+8*((k>>2)&1)+4*(k>>3).
__global__ __launch_bounds__(256) void k_qkv(const float* __restrict__ x,
                                             const float* __restrict__ g,
                                             const unsigned short* __restrict__ wq_bf,
                                             const float* __restrict__ rbuf,
                                             unsigned short* __restrict__ qbuf,
                                             unsigned short* __restrict__ kbuf,
                                             unsigned short* __restrict__ vbuf) {
  int bid = blockIdx.x;            // 768 = 4b * 6ot * 32pt
  int b = bid / 192;
  int rem = bid % 192;
  int ot = rem / 32;
  int pt = rem % 32;
  int o0 = ot * 64, p0 = pt * 128;

  __shared__ unsigned short xnT[128 * 40];

  int t = threadIdx.x;
  int lane = t & 63, w = t >> 6;
  int lr = lane & 15, lg = lane >> 4;
  int pl = t & 127, ch = t >> 7;

  float rr = rbuf[b * 4096 + p0 + pl];
  const float* xb = x + (size_t)b * 256 * 4096;
  const unsigned short* wqrow = wq_bf + (size_t)(o0 + w * 16 + lr) * 256;

  f32x4 acc[8];
  f32x4 z = {0.f, 0.f, 0.f, 0.f};
#pragma unroll
  for (int i = 0; i < 8; ++i) acc[i] = z;

  for (int c0 = 0; c0 < 256; c0 += 32) {
    __syncthreads();
#pragma unroll
    for (int i = 0; i < 8; ++i) {
      int c = ch * 16 + i * 2;
      float v0 = xb[(size_t)(c0 + c) * 4096 + p0 + pl];
      float v1 = xb[(size_t)(c0 + c + 1) * 4096 + p0 + pl];
      v0 = v0 * rr * g[c0 + c];
      v1 = v1 * rr * g[c0 + c + 1];
      unsigned int u = (unsigned int)f2bf(v0) | ((unsigned int)f2bf(v1) << 16);
      *(unsigned int*)&xnT[swz40(pl, c)] = u;
    }
    __syncthreads();
    short8 af = mk8(wqrow + c0 + lg * 8);
#pragma unroll
    for (int pt16 = 0; pt16 < 8; ++pt16) {
      short8 bf = mk8(&xnT[swz40(pt16 * 16 + lr, lg * 8)]);
      acc[pt16] = MFMA16(af, bf, acc[pt16]);
    }
  }

  int obase = o0 + w * 16 + lg * 4;          // multiple of 4
  if (obase < 256) {
    int isK = obase >= 128;
    int oh = obase - (isK ? 128 : 0);
    int h = oh >> 5, d0 = oh & 31;
    unsigned short* dst = (isK ? kbuf : qbuf) + ((size_t)(b * 4 + h) * 4096) * 32;
#pragma unroll
    for (int pt16 = 0; pt16 < 8; ++pt16) {
      int p = p0 + pt16 * 16 + lr;
      unsigned int u0 = pk2(acc[pt16][0], acc[pt16][1]);
      unsigned int u1 = pk2(acc[pt16][2], acc[pt16][3]);
      uint2 uu = {u0, u1};
      *(uint2*)(dst + (size_t)p * 32 + d0) = uu;
    }
  } else {
    int oh = obase - 256;
    int h = oh >> 5, d0 = oh & 31;
    unsigned short* dst = vbuf + ((size_t)(b * 4 + h) * 32) * 4096;
    // sigma: swap bits 2 and 3 of the within-block index (involution)
    int sl = (lr & 3) | ((lr & 4) << 1) | ((lr & 8) >> 1);
#pragma unroll
    for (int pt16 = 0; pt16 < 8; ++pt16) {
      int pp = p0 + pt16 * 16 + sl;
#pragma unroll
      for (int r = 0; r < 4; ++r)
        dst[(size_t)(d0 + r) * 4096 + pp] = f2bf(acc[pt16][r]);
    }
  }
}

// ---------------- kernel 3: flash attention, swapped-QK^T, LDS-free ----------------
// grid 512 = 16 bh x 32 q-tiles of 128; 4 waves x 32 q-rows each.
// S^T = mfma32(K, Q): lane owns q = lane&31; holds j = (reg&3)+8*(reg>>2)+4*hi.
// PV B-fragment = lane's own p[] words (V stored sigma-permuted to match).
__device__ __forceinline__ void attn_tile(short8 kf0, short8 kf1, short8 vf0, short8 vf1,
                                          short8 qf0, short8 qf1, const f32x16& z16,
                                          float& m, float& ms, float& lsum, f32x16& oacc) {
  const float cexp = 0.25505654427102996f;  // 32^-0.5 * log2(e)
  f32x16 s = MFMA32(kf0, qf0, z16);
  s = MFMA32(kf1, qf1, s);

  float m0 = fmaxf(fmaxf(s[0], s[1]), fmaxf(s[2], s[3]));
  float m1 = fmaxf(fmaxf(s[4], s[5]), fmaxf(s[6], s[7]));
  float m2 = fmaxf(fmaxf(s[8], s[9]), fmaxf(s[10], s[11]));
  float m3 = fmaxf(fmaxf(s[12], s[13]), fmaxf(s[14], s[15]));
  float pmax = redmax32(fmaxf(fmaxf(m0, m1), fmaxf(m2, m3)));

  // defer-max: rescale only when max grew by >8 exp2-units
  if (!__all(fmaf(pmax, cexp, -ms) <= 8.0f)) {
    float mn = fmaxf(m, pmax);
    float fac = __builtin_amdgcn_exp2f((m - mn) * cexp);
    m = mn;
    ms = mn * cexp;
    lsum *= fac;
#pragma unroll
    for (int i = 0; i < 16; ++i) oacc[i] *= fac;
  }

  float p[16];
#pragma unroll
  for (int i = 0; i < 16; ++i) p[i] = __builtin_amdgcn_exp2f(fmaf(s[i], cexp, -ms));

  float s0 = ((p[0] + p[1]) + (p[2] + p[3])) + ((p[4] + p[5]) + (p[6] + p[7]));
  float s1 = ((p[8] + p[9]) + (p[10] + p[11])) + ((p[12] + p[13]) + (p[14] + p[15]));
  lsum += s0 + s1;

  // Own-lane B-fragments: k-slot hi*8+i holds j = sigma(slot); V matches.
  uint4v u0 = {pk2(p[0], p[1]), pk2(p[2], p[3]), pk2(p[4], p[5]), pk2(p[6], p[7])};
  uint4v u1 = {pk2(p[8], p[9]), pk2(p[10], p[11]), pk2(p[12], p[13]), pk2(p[14], p[15])};

  oacc = MFMA32(vf0, __builtin_bit_cast(short8, u0), oacc);
  oacc = MFMA32(vf1, __builtin_bit_cast(short8, u1), oacc);
}

__global__ __launch_bounds__(256) void k_attn(const unsigned short* __restrict__ qbuf,
                                              const unsigned short* __restrict__ kbuf,
                                              const unsigned short* __restrict__ vbuf,
                                              unsigned short* __restrict__ attno) {
  int bid = blockIdx.x;
  int wid = ((bid & 7) << 6) | (bid >> 3);   // XCD-contiguous work mapping (512 % 8 == 0)
  int qt = wid & 31, bh = wid >> 5;
  int t = threadIdx.x, lane = t & 63, w = t >> 6;
  int l31 = lane & 31, hi = lane >> 5;

  const unsigned short* qg = qbuf + (size_t)bh * 4096 * 32;
  const unsigned short* kg = kbuf + (size_t)bh * 4096 * 32;
  const unsigned short* vg = vbuf + (size_t)bh * 32 * 4096;

  int qrow = qt * 128 + w * 32 + l31;
  short8 qf0 = mk8(qg + (size_t)qrow * 32 + hi * 8);
  short8 qf1 = mk8(qg + (size_t)qrow * 32 + 16 + hi * 8);

  const unsigned short* kl = kg + (size_t)l31 * 32 + hi * 8;    // + j*32
  const unsigned short* vl = vg + (size_t)l31 * 4096 + hi * 8;  // + jbase

  const f32x16 z16 = zero16();
  f32x16 oacc = zero16();
  float m = -1e30f, ms = -2.55e29f, lsum = 0.f;

  short8 kf0a = mk8(kl + 0), kf1a = mk8(kl + 16);
  short8 vf0a = mk8(vl + 0), vf1a = mk8(vl + 16);
  short8 kf0b, kf1b, vf0b, vf1b;

  for (int k0 = 0; k0 < 4096; k0 += 64) {
    size_t jb = (size_t)(k0 + 32);
    kf0b = mk8(kl + jb * 32);
    kf1b = mk8(kl + jb * 32 + 16);
    vf0b = mk8(vl + jb);
    vf1b = mk8(vl + jb + 16);
    attn_tile(kf0a, kf1a, vf0a, vf1a, qf0, qf1, z16, m, ms, lsum, oacc);

    size_t jn = (size_t)((k0 + 64) & 4095);
    kf0a = mk8(kl + jn * 32);
    kf1a = mk8(kl + jn * 32 + 16);
    vf0a = mk8(vl + jn);
    vf1a = mk8(vl + jn + 16);
    attn_tile(kf0b, kf1b, vf0b, vf1b, qf0, qf1, z16, m, ms, lsum, oacc);
  }

  lsum = redsum32(lsum);
  float rinv = 1.0f / lsum;

  int b = bh >> 2, h = bh & 3;
  unsigned short* ob = attno + ((size_t)b * 4096 + qrow) * 128 + h * 32;
#pragma unroll
  for (int r2 = 0; r2 < 8; ++r2) {
    int reg = r2 * 2;
    int dv = (reg & 3) + 8 * (reg >> 2) + 4 * hi;
    unsigned int u = pk2(oacc[reg] * rinv, oacc[reg + 1] * rinv);
    *(unsigned int*)(ob + dv) = u;
  }
}

// ---------------- kernel 4: output projection + bias ----------------
__global__ __launch_bounds__(256) void k_out(const unsigned short* __restrict__ attno,
                                             const unsigned short* __restrict__ wo_bf,
                                             const float* __restrict__ bo,
                                             float* __restrict__ out) {
  int bid = blockIdx.x;
  int b = bid >> 6;
  int p0 = (bid & 63) * 64;
  int t = threadIdx.x, lane = t & 63, w = t >> 6;
  int lr = lane & 15, lg = lane >> 4;

  f32x4 z = {0.f, 0.f, 0.f, 0.f};
  f32x4 acc[4][4];
#pragma unroll
  for (int i = 0; i < 4; ++i)
#pragma unroll
    for (int j = 0; j < 4; ++j) acc[i][j] = z;

  for (int c0 = 0; c0 < 128; c0 += 32) {
    short8 bfr[4];
#pragma unroll
    for (int pt16 = 0; pt16 < 4; ++pt16)
      bfr[pt16] = mk8(attno + (size_t)(b * 4096 + p0 + pt16 * 16 + lr) * 128 + c0 + lg * 8);
#pragma unroll
    for (int ct = 0; ct < 4; ++ct) {
      short8 afr = mk8(wo_bf + (size_t)(w * 64 + ct * 16 + lr) * 128 + c0 + lg * 8);
#pragma unroll
      for (int pt16 = 0; pt16 < 4; ++pt16)
        acc[ct][pt16] = MFMA16(afr, bfr[pt16], acc[ct][pt16]);
    }
  }

#pragma unroll
  for (int ct = 0; ct < 4; ++ct) {
#pragma unroll
    for (int pt16 = 0; pt16 < 4; ++pt16) {
#pragma unroll
      for (int r = 0; r < 4; ++r) {
        int co = w * 64 + ct * 16 + lg * 4 + r;
        int p = p0 + pt16 * 16 + lr;
        out[((size_t)b * 256 + co) * 4096 + p] = acc[ct][pt16][r] + bo[co];
      }
    }
  }
}

extern "C" void kernel_launch(void* const* d_in, const int* in_sizes, int n_in,
                              void* d_out, int out_size, void* d_ws, size_t ws_size,
                              hipStream_t stream) {
  const float* x = (const float*)d_in[0];
  const float* g = (const float*)d_in[1];
  const float* wq = (const float*)d_in[2];
  const float* wo = (const float*)d_in[3];
  const float* bo = (const float*)d_in[4];
  float* out = (float*)d_out;

  char* ws = (char*)d_ws;
  float* rbuf = (float*)ws;                                  // 65536 B
  unsigned short* wq_bf = (unsigned short*)(ws + 65536);     // 196608 B
  unsigned short* wo_bf = (unsigned short*)(ws + 262144);    // 65536 B
  unsigned short* qbuf = (unsigned short*)(ws + 327680);     // 4 MiB
  unsigned short* kbuf = (unsigned short*)(ws + 4521984);    // 4 MiB
  unsigned short* vbuf = (unsigned short*)(ws + 8716288);    // 4 MiB
  unsigned short* attno = (unsigned short*)(ws + 12910592);  // 4 MiB

  k_prep<<<dim3(384), dim3(256), 0, stream>>>(wq, wo, wq_bf, wo_bf);
  k_rms<<<dim3(256), dim3(256), 0, stream>>>(x, rbuf);
  k_qkv<<<dim3(768), dim3(256), 0, stream>>>(x, g, wq_bf, rbuf, qbuf, kbuf, vbuf);
  k_attn<<<dim3(512), dim3(256), 0, stream>>>(qbuf, kbuf, vbuf, attno);
  k_out<<<dim3(256), dim3(256), 0, stream>>>(attno, wo_bf, bo, out);
}